// Round 1
// 192.834 us; speedup vs baseline: 1.1865x; 1.1865x over previous
//
#include <hip/hip_runtime.h>
#include <hip/hip_bf16.h>

#define IN_CH 256
#define HC    128   // HEADS * C
#define HEADS 4
#define CPH   32    // channels per head
#define NEG_SLOPE 0.2f

// ---------- K_gemm: xp = x @ W   (M=n, N=128, K=256), f32 ----------
__global__ __launch_bounds__(256) void k_gemm(const float* __restrict__ x,
                                              const float* __restrict__ W,
                                              float* __restrict__ xp, int n) {
    __shared__ float As[8][128];
    __shared__ float Bs[8][128];
    const int tid = threadIdx.x;
    const int m0 = blockIdx.x * 128;
    const int tx = tid & 15;
    const int ty = tid >> 4;
    const int lr = tid >> 1;
    const int kp = tid & 1;

    float acc[8][8];
#pragma unroll
    for (int i = 0; i < 8; ++i)
#pragma unroll
        for (int j = 0; j < 8; ++j) acc[i][j] = 0.0f;

    for (int k0 = 0; k0 < IN_CH; k0 += 8) {
        float4 av = make_float4(0.f, 0.f, 0.f, 0.f);
        int gr = m0 + lr;
        if (gr < n)
            av = *(const float4*)(x + (size_t)gr * IN_CH + k0 + kp * 4);
        float4 bv = *(const float4*)(W + (size_t)(k0 + (tid >> 5)) * HC + (tid & 31) * 4);
        __syncthreads();
        As[kp * 4 + 0][lr] = av.x;
        As[kp * 4 + 1][lr] = av.y;
        As[kp * 4 + 2][lr] = av.z;
        As[kp * 4 + 3][lr] = av.w;
        *(float4*)(&Bs[tid >> 5][(tid & 31) * 4]) = bv;
        __syncthreads();
#pragma unroll
        for (int kk = 0; kk < 8; ++kk) {
            float a[8], b[8];
            *(float4*)(a)     = *(const float4*)(&As[kk][ty * 8]);
            *(float4*)(a + 4) = *(const float4*)(&As[kk][ty * 8 + 4]);
            *(float4*)(b)     = *(const float4*)(&Bs[kk][tx * 8]);
            *(float4*)(b + 4) = *(const float4*)(&Bs[kk][tx * 8 + 4]);
#pragma unroll
            for (int i = 0; i < 8; ++i)
#pragma unroll
                for (int j = 0; j < 8; ++j) acc[i][j] += a[i] * b[j];
        }
    }
#pragma unroll
    for (int i = 0; i < 8; ++i) {
        int r = m0 + ty * 8 + i;
        if (r < n) {
            *(float4*)(xp + (size_t)r * HC + tx * 8)     = *(float4*)(&acc[i][0]);
            *(float4*)(xp + (size_t)r * HC + tx * 8 + 4) = *(float4*)(&acc[i][4]);
        }
    }
}

// ---------- K_attdot: a_src[n,h], a_dst[n,h]; also cnt[node]=1 (self-loop) ----------
__global__ void k_attdot(const float* __restrict__ xp,
                         const float* __restrict__ att_src,
                         const float* __restrict__ att_dst,
                         float* __restrict__ asrc, float* __restrict__ adst,
                         int* __restrict__ cnt, int n) {
    int t = blockIdx.x * blockDim.x + threadIdx.x;
    if (t >= n * HEADS) return;
    int node = t >> 2, h = t & 3;
    if (h == 0) cnt[node] = 1;
    const float* row = xp + (size_t)node * HC + h * CPH;
    const float* as = att_src + h * CPH;
    const float* ad = att_dst + h * CPH;
    float s = 0.f, d = 0.f;
#pragma unroll
    for (int c = 0; c < CPH; ++c) {
        float v = row[c];
        s += v * as[c];
        d += v * ad[c];
    }
    asrc[t] = s;
    adst[t] = d;
}

// ---------- K_count ----------
__global__ void k_count(const int* __restrict__ ei, int* __restrict__ cnt, int E) {
    int e = blockIdx.x * blockDim.x + threadIdx.x;
    if (e >= E) return;
    atomicAdd(cnt + ei[E + e], 1);
}

// ---------- hierarchical scan: chunk=1024 ----------
// scan1: per-chunk reduce -> bsum[b]
__global__ __launch_bounds__(256) void k_scan1(const int* __restrict__ cnt,
                                               int* __restrict__ bsum, int n) {
    __shared__ int sm[256];
    int b = blockIdx.x, t = threadIdx.x;
    int base = b << 10;
    int s = 0;
#pragma unroll
    for (int j = 0; j < 4; ++j) {
        int i = base + t + j * 256;
        if (i < n) s += cnt[i];
    }
    sm[t] = s;
    __syncthreads();
    for (int d = 128; d > 0; d >>= 1) {
        if (t < d) sm[t] += sm[t + d];
        __syncthreads();
    }
    if (t == 0) bsum[b] = sm[0];
}

// scan2: exclusive scan of bsum (nb <= 1024); also offs[n] = total (known statically)
__global__ __launch_bounds__(1024) void k_scan2(int* __restrict__ bsum,
                                                int* __restrict__ offs,
                                                int nb, int n, int total) {
    __shared__ int sm[1024];
    int t = threadIdx.x;
    int orig = (t < nb) ? bsum[t] : 0;
    sm[t] = orig;
    __syncthreads();
    for (int d = 1; d < 1024; d <<= 1) {
        int v = (t >= d) ? sm[t - d] : 0;
        __syncthreads();
        sm[t] += v;
        __syncthreads();
    }
    if (t < nb) bsum[t] = sm[t] - orig;  // exclusive base per chunk
    if (t == 0) offs[n] = total;
}

// scan3: per-chunk exclusive scan (4 elems/thread) + chunk base -> offs, cursor
__global__ __launch_bounds__(256) void k_scan3(const int* __restrict__ cnt,
                                               const int* __restrict__ bsum,
                                               int* __restrict__ offs,
                                               int* __restrict__ cursor, int n) {
    __shared__ int sm[256];
    int b = blockIdx.x, t = threadIdx.x;
    int base = (b << 10) + t * 4;
    int c[4];
    int s = 0;
#pragma unroll
    for (int j = 0; j < 4; ++j) {
        int i = base + j;
        c[j] = (i < n) ? cnt[i] : 0;
        s += c[j];
    }
    sm[t] = s;
    __syncthreads();
    for (int d = 1; d < 256; d <<= 1) {
        int v = (t >= d) ? sm[t - d] : 0;
        __syncthreads();
        sm[t] += v;
        __syncthreads();
    }
    int excl = bsum[b] + ((t == 0) ? 0 : sm[t - 1]);
#pragma unroll
    for (int j = 0; j < 4; ++j) {
        int i = base + j;
        if (i < n) { offs[i] = excl; cursor[i] = excl; }
        excl += c[j];
    }
}

// ---------- K_fill ----------
__global__ void k_fill(const int* __restrict__ ei, int* __restrict__ cursor,
                       int* __restrict__ srcs, int E, int n) {
    int e = blockIdx.x * blockDim.x + threadIdx.x;
    if (e >= E + n) return;
    int s, d;
    if (e < E) { s = ei[e]; d = ei[E + e]; } else { s = d = e - E; }
    int pos = atomicAdd(cursor + d, 1);
    srcs[pos] = s;
}

// ---------- K_gat v2: one wave per dst node ----------
// pass 1: softmax stats (srcs staged via LDS).
// pass 2: 4 quarter-waves process 4 edges in parallel (8 in flight),
//         each lane owns 8 channels (2 x float4) -> coalesced 512B row/quarter.
__global__ __launch_bounds__(256) void k_gat(const int* __restrict__ offs,
                                             const int* __restrict__ srcs,
                                             const float* __restrict__ asrc,
                                             const float* __restrict__ adst,
                                             const float* __restrict__ xp,
                                             const float* __restrict__ bias,
                                             float* __restrict__ out, int n) {
    __shared__ int sS[4][128];
    const int wid = threadIdx.x >> 6;
    const int wave = blockIdx.x * 4 + wid;
    if (wave >= n) return;
    const int lane = threadIdx.x & 63;
    const int d = wave;
    const int start = offs[d], end = offs[d + 1];
    const int deg = end - start;

    const int h = lane & 3;
    const float ad_h = adst[(size_t)d * 4 + h];
    float m = -1e30f, Z = 0.f;

    // ---- pass 1: online softmax stats over chunks of <=128 edges ----
    for (int c0 = start; c0 < end; c0 += 128) {
        const int cn = min(128, end - c0);
        if (c0 + lane < end)      sS[wid][lane]      = srcs[c0 + lane];
        if (c0 + 64 + lane < end) sS[wid][64 + lane] = srcs[c0 + 64 + lane];
        asm volatile("s_waitcnt lgkmcnt(0)" ::: "memory");  // intra-wave LDS visibility
        for (int i = (lane >> 2); i < cn; i += 16) {
            int s = sS[wid][i];
            float t = asrc[(size_t)s * 4 + h] + ad_h;
            t = t > 0.f ? t : NEG_SLOPE * t;
            float nm = fmaxf(m, t);
            Z = Z * __expf(m - nm) + __expf(t - nm);
            m = nm;
        }
    }
#pragma unroll
    for (int off = 4; off < 64; off <<= 1) {
        float om = __shfl_xor(m, off, 64);
        float oZ = __shfl_xor(Z, off, 64);
        float nm = fmaxf(m, om);
        Z = Z * __expf(m - nm) + oZ * __expf(om - nm);
        m = nm;
    }

    // ---- pass 2 ----
    const int cl = lane & 15;   // channel lane: channels [cl*8, cl*8+8)
    const int eg = lane >> 4;   // edge slot (4 edges in parallel)
    const int hh = cl >> 2;     // head owning this channel slice
    const float m2  = __shfl(m, hh, 64);
    const float rZ  = 1.0f / __shfl(Z, hh, 64);
    const float ad2 = __shfl(ad_h, hh, 64);

    float4 a0 = make_float4(0.f, 0.f, 0.f, 0.f);
    float4 a1 = make_float4(0.f, 0.f, 0.f, 0.f);

    for (int c0 = start; c0 < end; c0 += 128) {
        const int cn = min(128, end - c0);
        if (deg > 128) {  // multi-chunk fallback: re-stage this chunk
            if (c0 + lane < end)      sS[wid][lane]      = srcs[c0 + lane];
            if (c0 + 64 + lane < end) sS[wid][64 + lane] = srcs[c0 + 64 + lane];
            asm volatile("s_waitcnt lgkmcnt(0)" ::: "memory");
        }
        const int full = cn & ~7;
        int i = 0;
        for (; i < full; i += 8) {  // 8 edges in flight, no guards
            int sa = sS[wid][i + eg];
            int sb = sS[wid][i + 4 + eg];
            float ta = asrc[(size_t)sa * 4 + hh] + ad2;
            float tb = asrc[(size_t)sb * 4 + hh] + ad2;
            const float4* xa = (const float4*)(xp + (size_t)sa * HC + cl * 8);
            const float4* xb = (const float4*)(xp + (size_t)sb * HC + cl * 8);
            float4 va0 = xa[0], va1 = xa[1];
            float4 vb0 = xb[0], vb1 = xb[1];
            ta = ta > 0.f ? ta : NEG_SLOPE * ta;
            tb = tb > 0.f ? tb : NEG_SLOPE * tb;
            float aa = __expf(ta - m2) * rZ;
            float ab = __expf(tb - m2) * rZ;
            a0.x += aa * va0.x; a0.y += aa * va0.y; a0.z += aa * va0.z; a0.w += aa * va0.w;
            a1.x += aa * va1.x; a1.y += aa * va1.y; a1.z += aa * va1.z; a1.w += aa * va1.w;
            a0.x += ab * vb0.x; a0.y += ab * vb0.y; a0.z += ab * vb0.z; a0.w += ab * vb0.w;
            a1.x += ab * vb1.x; a1.y += ab * vb1.y; a1.z += ab * vb1.z; a1.w += ab * vb1.w;
        }
        for (; i < cn; i += 4) {  // tail: exec-masked so no wasted row loads
            if (i + eg < cn) {
                int s = sS[wid][i + eg];
                float t = asrc[(size_t)s * 4 + hh] + ad2;
                const float4* xr = (const float4*)(xp + (size_t)s * HC + cl * 8);
                float4 v0 = xr[0], v1 = xr[1];
                t = t > 0.f ? t : NEG_SLOPE * t;
                float al = __expf(t - m2) * rZ;
                a0.x += al * v0.x; a0.y += al * v0.y; a0.z += al * v0.z; a0.w += al * v0.w;
                a1.x += al * v1.x; a1.y += al * v1.y; a1.z += al * v1.z; a1.w += al * v1.w;
            }
        }
    }

    // reduce across the 4 edge groups (lane bits 4 and 5)
#pragma unroll
    for (int off = 16; off < 64; off <<= 1) {
        a0.x += __shfl_xor(a0.x, off, 64); a0.y += __shfl_xor(a0.y, off, 64);
        a0.z += __shfl_xor(a0.z, off, 64); a0.w += __shfl_xor(a0.w, off, 64);
        a1.x += __shfl_xor(a1.x, off, 64); a1.y += __shfl_xor(a1.y, off, 64);
        a1.z += __shfl_xor(a1.z, off, 64); a1.w += __shfl_xor(a1.w, off, 64);
    }

    if (eg == 0) {
        const float4* bp = (const float4*)bias + cl * 2;
        float4 b0 = bp[0], b1 = bp[1];
        float4 o0, o1;
        o0.x = fmaxf(a0.x + b0.x, 0.f); o0.y = fmaxf(a0.y + b0.y, 0.f);
        o0.z = fmaxf(a0.z + b0.z, 0.f); o0.w = fmaxf(a0.w + b0.w, 0.f);
        o1.x = fmaxf(a1.x + b1.x, 0.f); o1.y = fmaxf(a1.y + b1.y, 0.f);
        o1.z = fmaxf(a1.z + b1.z, 0.f); o1.w = fmaxf(a1.w + b1.w, 0.f);
        float4* op = (float4*)(out + (size_t)d * HC) + cl * 2;
        op[0] = o0; op[1] = o1;
    }
}

extern "C" void kernel_launch(void* const* d_in, const int* in_sizes, int n_in,
                              void* d_out, int out_size, void* d_ws, size_t ws_size,
                              hipStream_t stream) {
    const float* x       = (const float*)d_in[0];
    const int*   ei      = (const int*)d_in[1];
    const float* W       = (const float*)d_in[3];
    const float* att_src = (const float*)d_in[4];
    const float* att_dst = (const float*)d_in[5];
    const float* bias    = (const float*)d_in[6];
    float* out = (float*)d_out;

    const int n = in_sizes[0] / IN_CH;   // 40000
    const int E = in_sizes[1] / 2;       // 640000
    const int EN = E + n;
    const int NB = (n + 1023) >> 10;     // scan chunks

    // workspace layout
    float* xp   = (float*)d_ws;                          // n*128 f32
    float* asrc = xp + (size_t)n * HC;                   // n*4
    float* adst = asrc + (size_t)n * HEADS;              // n*4
    int*   cnt    = (int*)(adst + (size_t)n * HEADS);    // n
    int*   offs   = cnt + n;                             // n+1
    int*   cursor = offs + n + 1;                        // n
    int*   bsum   = cursor + n;                          // NB
    int*   srcs   = bsum + 1024;                         // E+n

    k_gemm<<<dim3((n + 127) / 128), 256, 0, stream>>>(x, W, xp, n);
    k_attdot<<<(n * HEADS + 255) / 256, 256, 0, stream>>>(xp, att_src, att_dst, asrc, adst, cnt, n);
    k_count<<<(E + 255) / 256, 256, 0, stream>>>(ei, cnt, E);
    k_scan1<<<NB, 256, 0, stream>>>(cnt, bsum, n);
    k_scan2<<<1, 1024, 0, stream>>>(bsum, offs, NB, n, EN);
    k_scan3<<<NB, 256, 0, stream>>>(cnt, bsum, offs, cursor, n);
    k_fill<<<(EN + 255) / 256, 256, 0, stream>>>(ei, cursor, srcs, E, n);
    k_gat<<<(n + 3) / 4, 256, 0, stream>>>(offs, srcs, asrc, adst, xp, bias, out, n);
}

// Round 2
// 191.335 us; speedup vs baseline: 1.1958x; 1.0078x over previous
//
#include <hip/hip_runtime.h>
#include <hip/hip_bf16.h>

#define IN_CH 256
#define HC    128   // HEADS * C
#define HEADS 4
#define CPH   32    // channels per head
#define NEG_SLOPE 0.2f

// ---------- K_gemm v2: xp = x @ W (M=n, N=128, K=256), fused att-dot epilogue ----------
// 32x128 tile, 256 threads, grid = n/32 = 1250 blocks -> ~5 blocks/CU (vs 313 -> 1.2).
// As stored [k][row] with +2 pad: conflict-free b64 reads, 8B aligned (stride 136B).
__global__ __launch_bounds__(256) void k_gemm(const float* __restrict__ x,
                                              const float* __restrict__ W,
                                              const float* __restrict__ att_src,
                                              const float* __restrict__ att_dst,
                                              float* __restrict__ xp,
                                              float* __restrict__ asrc,
                                              float* __restrict__ adst,
                                              int* __restrict__ cnt, int n) {
    __shared__ float As[32][34];   // [k][row], pad 2
    __shared__ float Bs[32][128];  // [k][col]
    const int tid = threadIdx.x;
    const int m0 = blockIdx.x * 32;
    const int tx = tid & 15;       // 8 output cols each
    const int ty = tid >> 4;       // 2 output rows each

    const int lrow = tid >> 3;         // 0..31 x-row in tile
    const int lk4  = (tid & 7) * 4;    // k offset (float4)
    const int bcol = (tid & 31) * 4;   // W col (float4)
    const int brow = tid >> 5;         // W row base 0..7

    float acc[2][8];
#pragma unroll
    for (int i = 0; i < 2; ++i)
#pragma unroll
        for (int j = 0; j < 8; ++j) acc[i][j] = 0.f;

    const int gr = m0 + lrow;
    for (int k0 = 0; k0 < IN_CH; k0 += 32) {
        float4 av = make_float4(0.f, 0.f, 0.f, 0.f);
        if (gr < n) av = *(const float4*)(x + (size_t)gr * IN_CH + k0 + lk4);
        float4 bv[4];
#pragma unroll
        for (int j = 0; j < 4; ++j)
            bv[j] = *(const float4*)(W + (size_t)(k0 + brow + 8 * j) * HC + bcol);
        __syncthreads();
        As[lk4 + 0][lrow] = av.x;
        As[lk4 + 1][lrow] = av.y;
        As[lk4 + 2][lrow] = av.z;
        As[lk4 + 3][lrow] = av.w;
#pragma unroll
        for (int j = 0; j < 4; ++j)
            *(float4*)(&Bs[brow + 8 * j][bcol]) = bv[j];
        __syncthreads();
#pragma unroll 8
        for (int kk = 0; kk < 32; ++kk) {
            float a0 = As[kk][ty * 2];
            float a1 = As[kk][ty * 2 + 1];
            float b[8];
            *(float4*)(b)     = *(const float4*)(&Bs[kk][tx * 8]);
            *(float4*)(b + 4) = *(const float4*)(&Bs[kk][tx * 8 + 4]);
#pragma unroll
            for (int j = 0; j < 8; ++j) {
                acc[0][j] += a0 * b[j];
                acc[1][j] += a1 * b[j];
            }
        }
    }

    // epilogue: xp write + fused attention dots + cnt=1 (self-loop)
    const int hh = tx >> 2;  // this thread's 8 cols lie in head hh
    float4 vs0 = *(const float4*)(att_src + tx * 8);
    float4 vs1 = *(const float4*)(att_src + tx * 8 + 4);
    float4 vd0 = *(const float4*)(att_dst + tx * 8);
    float4 vd1 = *(const float4*)(att_dst + tx * 8 + 4);
#pragma unroll
    for (int i = 0; i < 2; ++i) {
        int r = m0 + ty * 2 + i;
        float s = acc[i][0] * vs0.x + acc[i][1] * vs0.y + acc[i][2] * vs0.z + acc[i][3] * vs0.w
                + acc[i][4] * vs1.x + acc[i][5] * vs1.y + acc[i][6] * vs1.z + acc[i][7] * vs1.w;
        float d = acc[i][0] * vd0.x + acc[i][1] * vd0.y + acc[i][2] * vd0.z + acc[i][3] * vd0.w
                + acc[i][4] * vd1.x + acc[i][5] * vd1.y + acc[i][6] * vd1.z + acc[i][7] * vd1.w;
        // reduce over the 4 lanes of this head (tx&3)
        s += __shfl_xor(s, 1, 64); s += __shfl_xor(s, 2, 64);
        d += __shfl_xor(d, 1, 64); d += __shfl_xor(d, 2, 64);
        if (r < n) {
            *(float4*)(xp + (size_t)r * HC + tx * 8)     = *(float4*)(&acc[i][0]);
            *(float4*)(xp + (size_t)r * HC + tx * 8 + 4) = *(float4*)(&acc[i][4]);
            if ((tx & 3) == 0) {
                asrc[(size_t)r * 4 + hh] = s;
                adst[(size_t)r * 4 + hh] = d;
            }
            if (tx == 0) cnt[r] = 1;
        }
    }
}

// ---------- K_count ----------
__global__ void k_count(const int* __restrict__ ei, int* __restrict__ cnt, int E) {
    int e = blockIdx.x * blockDim.x + threadIdx.x;
    if (e >= E) return;
    atomicAdd(cnt + ei[E + e], 1);
}

// ---------- hierarchical scan: chunk=1024 ----------
// scan1: per-chunk reduce -> bsum[b]
__global__ __launch_bounds__(256) void k_scan1(const int* __restrict__ cnt,
                                               int* __restrict__ bsum, int n) {
    __shared__ int sm[256];
    int b = blockIdx.x, t = threadIdx.x;
    int base = b << 10;
    int s = 0;
#pragma unroll
    for (int j = 0; j < 4; ++j) {
        int i = base + t + j * 256;
        if (i < n) s += cnt[i];
    }
    sm[t] = s;
    __syncthreads();
    for (int d = 128; d > 0; d >>= 1) {
        if (t < d) sm[t] += sm[t + d];
        __syncthreads();
    }
    if (t == 0) bsum[b] = sm[0];
}

// scan2: exclusive scan of bsum (nb <= 1024); also offs[n] = total (known statically)
__global__ __launch_bounds__(1024) void k_scan2(int* __restrict__ bsum,
                                                int* __restrict__ offs,
                                                int nb, int n, int total) {
    __shared__ int sm[1024];
    int t = threadIdx.x;
    int orig = (t < nb) ? bsum[t] : 0;
    sm[t] = orig;
    __syncthreads();
    for (int d = 1; d < 1024; d <<= 1) {
        int v = (t >= d) ? sm[t - d] : 0;
        __syncthreads();
        sm[t] += v;
        __syncthreads();
    }
    if (t < nb) bsum[t] = sm[t] - orig;  // exclusive base per chunk
    if (t == 0) offs[n] = total;
}

// scan3: per-chunk exclusive scan (4 elems/thread) + chunk base -> offs, cursor
__global__ __launch_bounds__(256) void k_scan3(const int* __restrict__ cnt,
                                               const int* __restrict__ bsum,
                                               int* __restrict__ offs,
                                               int* __restrict__ cursor, int n) {
    __shared__ int sm[256];
    int b = blockIdx.x, t = threadIdx.x;
    int base = (b << 10) + t * 4;
    int c[4];
    int s = 0;
#pragma unroll
    for (int j = 0; j < 4; ++j) {
        int i = base + j;
        c[j] = (i < n) ? cnt[i] : 0;
        s += c[j];
    }
    sm[t] = s;
    __syncthreads();
    for (int d = 1; d < 256; d <<= 1) {
        int v = (t >= d) ? sm[t - d] : 0;
        __syncthreads();
        sm[t] += v;
        __syncthreads();
    }
    int excl = bsum[b] + ((t == 0) ? 0 : sm[t - 1]);
#pragma unroll
    for (int j = 0; j < 4; ++j) {
        int i = base + j;
        if (i < n) { offs[i] = excl; cursor[i] = excl; }
        excl += c[j];
    }
}

// ---------- K_fill ----------
__global__ void k_fill(const int* __restrict__ ei, int* __restrict__ cursor,
                       int* __restrict__ srcs, int E, int n) {
    int e = blockIdx.x * blockDim.x + threadIdx.x;
    if (e >= E + n) return;
    int s, d;
    if (e < E) { s = ei[e]; d = ei[E + e]; } else { s = d = e - E; }
    int pos = atomicAdd(cursor + d, 1);
    srcs[pos] = s;
}

// ---------- K_gat: one wave per dst node ----------
// pass 1: softmax stats (srcs staged via LDS).
// pass 2: 4 quarter-waves process 4 edges in parallel (8 in flight),
//         each lane owns 8 channels (2 x float4) -> coalesced 512B row/quarter.
__global__ __launch_bounds__(256) void k_gat(const int* __restrict__ offs,
                                             const int* __restrict__ srcs,
                                             const float* __restrict__ asrc,
                                             const float* __restrict__ adst,
                                             const float* __restrict__ xp,
                                             const float* __restrict__ bias,
                                             float* __restrict__ out, int n) {
    __shared__ int sS[4][128];
    const int wid = threadIdx.x >> 6;
    const int wave = blockIdx.x * 4 + wid;
    if (wave >= n) return;
    const int lane = threadIdx.x & 63;
    const int d = wave;
    const int start = offs[d], end = offs[d + 1];
    const int deg = end - start;

    const int h = lane & 3;
    const float ad_h = adst[(size_t)d * 4 + h];
    float m = -1e30f, Z = 0.f;

    // ---- pass 1: online softmax stats over chunks of <=128 edges ----
    for (int c0 = start; c0 < end; c0 += 128) {
        const int cn = min(128, end - c0);
        if (c0 + lane < end)      sS[wid][lane]      = srcs[c0 + lane];
        if (c0 + 64 + lane < end) sS[wid][64 + lane] = srcs[c0 + 64 + lane];
        asm volatile("s_waitcnt lgkmcnt(0)" ::: "memory");  // intra-wave LDS visibility
        for (int i = (lane >> 2); i < cn; i += 16) {
            int s = sS[wid][i];
            float t = asrc[(size_t)s * 4 + h] + ad_h;
            t = t > 0.f ? t : NEG_SLOPE * t;
            float nm = fmaxf(m, t);
            Z = Z * __expf(m - nm) + __expf(t - nm);
            m = nm;
        }
    }
#pragma unroll
    for (int off = 4; off < 64; off <<= 1) {
        float om = __shfl_xor(m, off, 64);
        float oZ = __shfl_xor(Z, off, 64);
        float nm = fmaxf(m, om);
        Z = Z * __expf(m - nm) + oZ * __expf(om - nm);
        m = nm;
    }

    // ---- pass 2 ----
    const int cl = lane & 15;   // channel lane: channels [cl*8, cl*8+8)
    const int eg = lane >> 4;   // edge slot (4 edges in parallel)
    const int hh = cl >> 2;     // head owning this channel slice
    const float m2  = __shfl(m, hh, 64);
    const float rZ  = 1.0f / __shfl(Z, hh, 64);
    const float ad2 = __shfl(ad_h, hh, 64);

    float4 a0 = make_float4(0.f, 0.f, 0.f, 0.f);
    float4 a1 = make_float4(0.f, 0.f, 0.f, 0.f);

    for (int c0 = start; c0 < end; c0 += 128) {
        const int cn = min(128, end - c0);
        if (deg > 128) {  // multi-chunk fallback: re-stage this chunk
            if (c0 + lane < end)      sS[wid][lane]      = srcs[c0 + lane];
            if (c0 + 64 + lane < end) sS[wid][64 + lane] = srcs[c0 + 64 + lane];
            asm volatile("s_waitcnt lgkmcnt(0)" ::: "memory");
        }
        const int full = cn & ~7;
        int i = 0;
        for (; i < full; i += 8) {  // 8 edges in flight, no guards
            int sa = sS[wid][i + eg];
            int sb = sS[wid][i + 4 + eg];
            float ta = asrc[(size_t)sa * 4 + hh] + ad2;
            float tb = asrc[(size_t)sb * 4 + hh] + ad2;
            const float4* xa = (const float4*)(xp + (size_t)sa * HC + cl * 8);
            const float4* xb = (const float4*)(xp + (size_t)sb * HC + cl * 8);
            float4 va0 = xa[0], va1 = xa[1];
            float4 vb0 = xb[0], vb1 = xb[1];
            ta = ta > 0.f ? ta : NEG_SLOPE * ta;
            tb = tb > 0.f ? tb : NEG_SLOPE * tb;
            float aa = __expf(ta - m2) * rZ;
            float ab = __expf(tb - m2) * rZ;
            a0.x += aa * va0.x; a0.y += aa * va0.y; a0.z += aa * va0.z; a0.w += aa * va0.w;
            a1.x += aa * va1.x; a1.y += aa * va1.y; a1.z += aa * va1.z; a1.w += aa * va1.w;
            a0.x += ab * vb0.x; a0.y += ab * vb0.y; a0.z += ab * vb0.z; a0.w += ab * vb0.w;
            a1.x += ab * vb1.x; a1.y += ab * vb1.y; a1.z += ab * vb1.z; a1.w += ab * vb1.w;
        }
        for (; i < cn; i += 4) {  // tail: exec-masked so no wasted row loads
            if (i + eg < cn) {
                int s = sS[wid][i + eg];
                float t = asrc[(size_t)s * 4 + hh] + ad2;
                const float4* xr = (const float4*)(xp + (size_t)s * HC + cl * 8);
                float4 v0 = xr[0], v1 = xr[1];
                t = t > 0.f ? t : NEG_SLOPE * t;
                float al = __expf(t - m2) * rZ;
                a0.x += al * v0.x; a0.y += al * v0.y; a0.z += al * v0.z; a0.w += al * v0.w;
                a1.x += al * v1.x; a1.y += al * v1.y; a1.z += al * v1.z; a1.w += al * v1.w;
            }
        }
    }

    // reduce across the 4 edge groups (lane bits 4 and 5)
#pragma unroll
    for (int off = 16; off < 64; off <<= 1) {
        a0.x += __shfl_xor(a0.x, off, 64); a0.y += __shfl_xor(a0.y, off, 64);
        a0.z += __shfl_xor(a0.z, off, 64); a0.w += __shfl_xor(a0.w, off, 64);
        a1.x += __shfl_xor(a1.x, off, 64); a1.y += __shfl_xor(a1.y, off, 64);
        a1.z += __shfl_xor(a1.z, off, 64); a1.w += __shfl_xor(a1.w, off, 64);
    }

    if (eg == 0) {
        const float4* bp = (const float4*)bias + cl * 2;
        float4 b0 = bp[0], b1 = bp[1];
        float4 o0, o1;
        o0.x = fmaxf(a0.x + b0.x, 0.f); o0.y = fmaxf(a0.y + b0.y, 0.f);
        o0.z = fmaxf(a0.z + b0.z, 0.f); o0.w = fmaxf(a0.w + b0.w, 0.f);
        o1.x = fmaxf(a1.x + b1.x, 0.f); o1.y = fmaxf(a1.y + b1.y, 0.f);
        o1.z = fmaxf(a1.z + b1.z, 0.f); o1.w = fmaxf(a1.w + b1.w, 0.f);
        float4* op = (float4*)(out + (size_t)d * HC) + cl * 2;
        op[0] = o0; op[1] = o1;
    }
}

extern "C" void kernel_launch(void* const* d_in, const int* in_sizes, int n_in,
                              void* d_out, int out_size, void* d_ws, size_t ws_size,
                              hipStream_t stream) {
    const float* x       = (const float*)d_in[0];
    const int*   ei      = (const int*)d_in[1];
    const float* W       = (const float*)d_in[3];
    const float* att_src = (const float*)d_in[4];
    const float* att_dst = (const float*)d_in[5];
    const float* bias    = (const float*)d_in[6];
    float* out = (float*)d_out;

    const int n = in_sizes[0] / IN_CH;   // 40000
    const int E = in_sizes[1] / 2;       // 640000
    const int EN = E + n;
    const int NB = (n + 1023) >> 10;     // scan chunks

    // workspace layout
    float* xp   = (float*)d_ws;                          // n*128 f32
    float* asrc = xp + (size_t)n * HC;                   // n*4
    float* adst = asrc + (size_t)n * HEADS;              // n*4
    int*   cnt    = (int*)(adst + (size_t)n * HEADS);    // n
    int*   offs   = cnt + n;                             // n+1
    int*   cursor = offs + n + 1;                        // n
    int*   bsum   = cursor + n;                          // NB
    int*   srcs   = bsum + 1024;                         // E+n

    k_gemm<<<dim3((n + 31) / 32), 256, 0, stream>>>(x, W, att_src, att_dst, xp, asrc, adst, cnt, n);
    k_count<<<(E + 255) / 256, 256, 0, stream>>>(ei, cnt, E);
    k_scan1<<<NB, 256, 0, stream>>>(cnt, bsum, n);
    k_scan2<<<1, 1024, 0, stream>>>(bsum, offs, NB, n, EN);
    k_scan3<<<NB, 256, 0, stream>>>(cnt, bsum, offs, cursor, n);
    k_fill<<<(EN + 255) / 256, 256, 0, stream>>>(ei, cursor, srcs, E, n);
    k_gat<<<(n + 3) / 4, 256, 0, stream>>>(offs, srcs, asrc, adst, xp, bias, out, n);
}

// Round 3
// 176.258 us; speedup vs baseline: 1.2981x; 1.0855x over previous
//
#include <hip/hip_runtime.h>
#include <hip/hip_bf16.h>

#define IN_CH 256
#define HC    128   // HEADS * C
#define HEADS 4
#define CPH   32    // channels per head
#define NEG_SLOPE 0.2f
#define BM 64
#define BK 16

// ---------- K_gemm v3: xp = x @ W (M=n, N=128, K=256), fused att-dot epilogue ----------
// 64x128 tile, 256 threads, double-buffered LDS + register prefetch:
//   global loads for chunk c+1 issue BEFORE compute of chunk c -> HBM/L2 latency
//   hides under 16kk x 32 FMA of compute. Only LDS-write + 2 barriers exposed.
// As stored [k][row] stride 68 (16B-aligned b128 reads, 2-way banks = free).
// Epilogue: attdots staged in LDS, dumped as coalesced float4 rows (no 4B scatter).
__global__ __launch_bounds__(256) void k_gemm(const float* __restrict__ x,
                                              const float* __restrict__ W,
                                              const float* __restrict__ att_src,
                                              const float* __restrict__ att_dst,
                                              float* __restrict__ xp,
                                              float* __restrict__ asrc,
                                              float* __restrict__ adst,
                                              int* __restrict__ cnt, int n) {
    __shared__ float As[2][BK][68];
    __shared__ float Bs[2][BK][128];
    const int tid = threadIdx.x;
    const int m0 = blockIdx.x * BM;
    const int tx = tid & 15;       // 8 output cols
    const int ty = tid >> 4;       // 4 output rows (ty*4 .. ty*4+3)

    // loader roles
    const int arow = tid >> 2;          // 0..63  (x row in tile)
    const int ak   = (tid & 3) * 4;     // 0,4,8,12 (k offset, float4)
    const int bcol = (tid & 31) * 4;    // W col (float4)
    const int brow = tid >> 5;          // W row 0..7 (+8)

    float acc[4][8];
#pragma unroll
    for (int i = 0; i < 4; ++i)
#pragma unroll
        for (int j = 0; j < 8; ++j) acc[i][j] = 0.f;

    const bool aval = (m0 + arow) < n;
    const float* xrow = x + (size_t)(m0 + arow) * IN_CH + ak;

    float4 xa = make_float4(0.f, 0.f, 0.f, 0.f);
    if (aval) xa = *(const float4*)(xrow);
    float4 wb0 = *(const float4*)(W + (size_t)brow * HC + bcol);
    float4 wb1 = *(const float4*)(W + (size_t)(brow + 8) * HC + bcol);

    As[0][ak + 0][arow] = xa.x;
    As[0][ak + 1][arow] = xa.y;
    As[0][ak + 2][arow] = xa.z;
    As[0][ak + 3][arow] = xa.w;
    *(float4*)(&Bs[0][brow][bcol])     = wb0;
    *(float4*)(&Bs[0][brow + 8][bcol]) = wb1;
    __syncthreads();

    const int NCH = IN_CH / BK;  // 16
    for (int c = 0; c < NCH; ++c) {
        const int cur = c & 1;
        if (c + 1 < NCH) {  // prefetch next chunk into registers (latency hides under compute)
            const int k0 = (c + 1) * BK;
            xa = make_float4(0.f, 0.f, 0.f, 0.f);
            if (aval) xa = *(const float4*)(xrow + k0);
            wb0 = *(const float4*)(W + (size_t)(k0 + brow) * HC + bcol);
            wb1 = *(const float4*)(W + (size_t)(k0 + brow + 8) * HC + bcol);
        }
#pragma unroll
        for (int kk = 0; kk < BK; ++kk) {
            float a[4], b[8];
            *(float4*)(a)     = *(const float4*)(&As[cur][kk][ty * 4]);
            *(float4*)(b)     = *(const float4*)(&Bs[cur][kk][tx * 8]);
            *(float4*)(b + 4) = *(const float4*)(&Bs[cur][kk][tx * 8 + 4]);
#pragma unroll
            for (int i = 0; i < 4; ++i)
#pragma unroll
                for (int j = 0; j < 8; ++j) acc[i][j] += a[i] * b[j];
        }
        if (c + 1 < NCH) {
            __syncthreads();  // everyone done reading the buffer we are about to overwrite
            const int nxt = cur ^ 1;
            As[nxt][ak + 0][arow] = xa.x;
            As[nxt][ak + 1][arow] = xa.y;
            As[nxt][ak + 2][arow] = xa.z;
            As[nxt][ak + 3][arow] = xa.w;
            *(float4*)(&Bs[nxt][brow][bcol])     = wb0;
            *(float4*)(&Bs[nxt][brow + 8][bcol]) = wb1;
            __syncthreads();  // writes visible before next compute
        }
    }

    // ---- epilogue: xp write + fused attention dots (coalesced via LDS staging) ----
    __syncthreads();
    float* sE = (float*)As;  // reuse: 512 floats needed, plenty of room

    float4 vs0 = *(const float4*)(att_src + tx * 8);
    float4 vs1 = *(const float4*)(att_src + tx * 8 + 4);
    float4 vd0 = *(const float4*)(att_dst + tx * 8);
    float4 vd1 = *(const float4*)(att_dst + tx * 8 + 4);
#pragma unroll
    for (int i = 0; i < 4; ++i) {
        const int r = ty * 4 + i;       // local row 0..63
        const int gr = m0 + r;
        float s = acc[i][0] * vs0.x + acc[i][1] * vs0.y + acc[i][2] * vs0.z + acc[i][3] * vs0.w
                + acc[i][4] * vs1.x + acc[i][5] * vs1.y + acc[i][6] * vs1.z + acc[i][7] * vs1.w;
        float d = acc[i][0] * vd0.x + acc[i][1] * vd0.y + acc[i][2] * vd0.z + acc[i][3] * vd0.w
                + acc[i][4] * vd1.x + acc[i][5] * vd1.y + acc[i][6] * vd1.z + acc[i][7] * vd1.w;
        s += __shfl_xor(s, 1, 64); s += __shfl_xor(s, 2, 64);
        d += __shfl_xor(d, 1, 64); d += __shfl_xor(d, 2, 64);
        if ((tx & 3) == 0) {
            sE[r * 4 + (tx >> 2)]       = s;
            sE[256 + r * 4 + (tx >> 2)] = d;
        }
        if (gr < n) {
            *(float4*)(xp + (size_t)gr * HC + tx * 8)     = *(float4*)(&acc[i][0]);
            *(float4*)(xp + (size_t)gr * HC + tx * 8 + 4) = *(float4*)(&acc[i][4]);
        }
    }
    __syncthreads();
    if (tid < 64) {
        if (m0 + tid < n) ((float4*)asrc)[m0 + tid] = ((const float4*)sE)[tid];
    } else if (tid < 128) {
        const int r = tid - 64;
        if (m0 + r < n) ((float4*)adst)[m0 + r] = ((const float4*)sE)[64 + r];
    } else if (tid < 192) {
        const int r = tid - 128;
        if (m0 + r < n) cnt[m0 + r] = 1;
    }
}

// ---------- K_count ----------
__global__ void k_count(const int* __restrict__ ei, int* __restrict__ cnt, int E) {
    int e = blockIdx.x * blockDim.x + threadIdx.x;
    if (e >= E) return;
    atomicAdd(cnt + ei[E + e], 1);
}

// ---------- hierarchical scan: chunk=1024 ----------
// scan1: per-chunk reduce -> bsum[b]
__global__ __launch_bounds__(256) void k_scan1(const int* __restrict__ cnt,
                                               int* __restrict__ bsum, int n) {
    __shared__ int sm[256];
    int b = blockIdx.x, t = threadIdx.x;
    int base = b << 10;
    int s = 0;
#pragma unroll
    for (int j = 0; j < 4; ++j) {
        int i = base + t + j * 256;
        if (i < n) s += cnt[i];
    }
    sm[t] = s;
    __syncthreads();
    for (int d = 128; d > 0; d >>= 1) {
        if (t < d) sm[t] += sm[t + d];
        __syncthreads();
    }
    if (t == 0) bsum[b] = sm[0];
}

// scan2: exclusive scan of bsum (nb <= 1024); also offs[n] = total (known statically)
__global__ __launch_bounds__(1024) void k_scan2(int* __restrict__ bsum,
                                                int* __restrict__ offs,
                                                int nb, int n, int total) {
    __shared__ int sm[1024];
    int t = threadIdx.x;
    int orig = (t < nb) ? bsum[t] : 0;
    sm[t] = orig;
    __syncthreads();
    for (int d = 1; d < 1024; d <<= 1) {
        int v = (t >= d) ? sm[t - d] : 0;
        __syncthreads();
        sm[t] += v;
        __syncthreads();
    }
    if (t < nb) bsum[t] = sm[t] - orig;  // exclusive base per chunk
    if (t == 0) offs[n] = total;
}

// scan3: per-chunk exclusive scan (4 elems/thread) + chunk base -> offs, cursor
__global__ __launch_bounds__(256) void k_scan3(const int* __restrict__ cnt,
                                               const int* __restrict__ bsum,
                                               int* __restrict__ offs,
                                               int* __restrict__ cursor, int n) {
    __shared__ int sm[256];
    int b = blockIdx.x, t = threadIdx.x;
    int base = (b << 10) + t * 4;
    int c[4];
    int s = 0;
#pragma unroll
    for (int j = 0; j < 4; ++j) {
        int i = base + j;
        c[j] = (i < n) ? cnt[i] : 0;
        s += c[j];
    }
    sm[t] = s;
    __syncthreads();
    for (int d = 1; d < 256; d <<= 1) {
        int v = (t >= d) ? sm[t - d] : 0;
        __syncthreads();
        sm[t] += v;
        __syncthreads();
    }
    int excl = bsum[b] + ((t == 0) ? 0 : sm[t - 1]);
#pragma unroll
    for (int j = 0; j < 4; ++j) {
        int i = base + j;
        if (i < n) { offs[i] = excl; cursor[i] = excl; }
        excl += c[j];
    }
}

// ---------- K_fill ----------
__global__ void k_fill(const int* __restrict__ ei, int* __restrict__ cursor,
                       int* __restrict__ srcs, int E, int n) {
    int e = blockIdx.x * blockDim.x + threadIdx.x;
    if (e >= E + n) return;
    int s, d;
    if (e < E) { s = ei[e]; d = ei[E + e]; } else { s = d = e - E; }
    int pos = atomicAdd(cursor + d, 1);
    srcs[pos] = s;
}

// ---------- K_gat: one wave per dst node ----------
// pass 1: softmax stats (srcs staged via LDS).
// pass 2: 4 quarter-waves process 4 edges in parallel (8 in flight),
//         each lane owns 8 channels (2 x float4) -> coalesced 512B row/quarter.
__global__ __launch_bounds__(256) void k_gat(const int* __restrict__ offs,
                                             const int* __restrict__ srcs,
                                             const float* __restrict__ asrc,
                                             const float* __restrict__ adst,
                                             const float* __restrict__ xp,
                                             const float* __restrict__ bias,
                                             float* __restrict__ out, int n) {
    __shared__ int sS[4][128];
    const int wid = threadIdx.x >> 6;
    const int wave = blockIdx.x * 4 + wid;
    if (wave >= n) return;
    const int lane = threadIdx.x & 63;
    const int d = wave;
    const int start = offs[d], end = offs[d + 1];
    const int deg = end - start;

    const int h = lane & 3;
    const float ad_h = adst[(size_t)d * 4 + h];
    float m = -1e30f, Z = 0.f;

    // ---- pass 1: online softmax stats over chunks of <=128 edges ----
    for (int c0 = start; c0 < end; c0 += 128) {
        const int cn = min(128, end - c0);
        if (c0 + lane < end)      sS[wid][lane]      = srcs[c0 + lane];
        if (c0 + 64 + lane < end) sS[wid][64 + lane] = srcs[c0 + 64 + lane];
        asm volatile("s_waitcnt lgkmcnt(0)" ::: "memory");  // intra-wave LDS visibility
        for (int i = (lane >> 2); i < cn; i += 16) {
            int s = sS[wid][i];
            float t = asrc[(size_t)s * 4 + h] + ad_h;
            t = t > 0.f ? t : NEG_SLOPE * t;
            float nm = fmaxf(m, t);
            Z = Z * __expf(m - nm) + __expf(t - nm);
            m = nm;
        }
    }
#pragma unroll
    for (int off = 4; off < 64; off <<= 1) {
        float om = __shfl_xor(m, off, 64);
        float oZ = __shfl_xor(Z, off, 64);
        float nm = fmaxf(m, om);
        Z = Z * __expf(m - nm) + oZ * __expf(om - nm);
        m = nm;
    }

    // ---- pass 2 ----
    const int cl = lane & 15;   // channel lane: channels [cl*8, cl*8+8)
    const int eg = lane >> 4;   // edge slot (4 edges in parallel)
    const int hh = cl >> 2;     // head owning this channel slice
    const float m2  = __shfl(m, hh, 64);
    const float rZ  = 1.0f / __shfl(Z, hh, 64);
    const float ad2 = __shfl(ad_h, hh, 64);

    float4 a0 = make_float4(0.f, 0.f, 0.f, 0.f);
    float4 a1 = make_float4(0.f, 0.f, 0.f, 0.f);

    for (int c0 = start; c0 < end; c0 += 128) {
        const int cn = min(128, end - c0);
        if (deg > 128) {  // multi-chunk fallback: re-stage this chunk
            if (c0 + lane < end)      sS[wid][lane]      = srcs[c0 + lane];
            if (c0 + 64 + lane < end) sS[wid][64 + lane] = srcs[c0 + 64 + lane];
            asm volatile("s_waitcnt lgkmcnt(0)" ::: "memory");
        }
        const int full = cn & ~7;
        int i = 0;
        for (; i < full; i += 8) {  // 8 edges in flight, no guards
            int sa = sS[wid][i + eg];
            int sb = sS[wid][i + 4 + eg];
            float ta = asrc[(size_t)sa * 4 + hh] + ad2;
            float tb = asrc[(size_t)sb * 4 + hh] + ad2;
            const float4* xa = (const float4*)(xp + (size_t)sa * HC + cl * 8);
            const float4* xb = (const float4*)(xp + (size_t)sb * HC + cl * 8);
            float4 va0 = xa[0], va1 = xa[1];
            float4 vb0 = xb[0], vb1 = xb[1];
            ta = ta > 0.f ? ta : NEG_SLOPE * ta;
            tb = tb > 0.f ? tb : NEG_SLOPE * tb;
            float aa = __expf(ta - m2) * rZ;
            float ab = __expf(tb - m2) * rZ;
            a0.x += aa * va0.x; a0.y += aa * va0.y; a0.z += aa * va0.z; a0.w += aa * va0.w;
            a1.x += aa * va1.x; a1.y += aa * va1.y; a1.z += aa * va1.z; a1.w += aa * va1.w;
            a0.x += ab * vb0.x; a0.y += ab * vb0.y; a0.z += ab * vb0.z; a0.w += ab * vb0.w;
            a1.x += ab * vb1.x; a1.y += ab * vb1.y; a1.z += ab * vb1.z; a1.w += ab * vb1.w;
        }
        for (; i < cn; i += 4) {  // tail: exec-masked so no wasted row loads
            if (i + eg < cn) {
                int s = sS[wid][i + eg];
                float t = asrc[(size_t)s * 4 + hh] + ad2;
                const float4* xr = (const float4*)(xp + (size_t)s * HC + cl * 8);
                float4 v0 = xr[0], v1 = xr[1];
                t = t > 0.f ? t : NEG_SLOPE * t;
                float al = __expf(t - m2) * rZ;
                a0.x += al * v0.x; a0.y += al * v0.y; a0.z += al * v0.z; a0.w += al * v0.w;
                a1.x += al * v1.x; a1.y += al * v1.y; a1.z += al * v1.z; a1.w += al * v1.w;
            }
        }
    }

    // reduce across the 4 edge groups (lane bits 4 and 5)
#pragma unroll
    for (int off = 16; off < 64; off <<= 1) {
        a0.x += __shfl_xor(a0.x, off, 64); a0.y += __shfl_xor(a0.y, off, 64);
        a0.z += __shfl_xor(a0.z, off, 64); a0.w += __shfl_xor(a0.w, off, 64);
        a1.x += __shfl_xor(a1.x, off, 64); a1.y += __shfl_xor(a1.y, off, 64);
        a1.z += __shfl_xor(a1.z, off, 64); a1.w += __shfl_xor(a1.w, off, 64);
    }

    if (eg == 0) {
        const float4* bp = (const float4*)bias + cl * 2;
        float4 b0 = bp[0], b1 = bp[1];
        float4 o0, o1;
        o0.x = fmaxf(a0.x + b0.x, 0.f); o0.y = fmaxf(a0.y + b0.y, 0.f);
        o0.z = fmaxf(a0.z + b0.z, 0.f); o0.w = fmaxf(a0.w + b0.w, 0.f);
        o1.x = fmaxf(a1.x + b1.x, 0.f); o1.y = fmaxf(a1.y + b1.y, 0.f);
        o1.z = fmaxf(a1.z + b1.z, 0.f); o1.w = fmaxf(a1.w + b1.w, 0.f);
        float4* op = (float4*)(out + (size_t)d * HC) + cl * 2;
        op[0] = o0; op[1] = o1;
    }
}

extern "C" void kernel_launch(void* const* d_in, const int* in_sizes, int n_in,
                              void* d_out, int out_size, void* d_ws, size_t ws_size,
                              hipStream_t stream) {
    const float* x       = (const float*)d_in[0];
    const int*   ei      = (const int*)d_in[1];
    const float* W       = (const float*)d_in[3];
    const float* att_src = (const float*)d_in[4];
    const float* att_dst = (const float*)d_in[5];
    const float* bias    = (const float*)d_in[6];
    float* out = (float*)d_out;

    const int n = in_sizes[0] / IN_CH;   // 40000
    const int E = in_sizes[1] / 2;       // 640000
    const int EN = E + n;
    const int NB = (n + 1023) >> 10;     // scan chunks

    // workspace layout
    float* xp   = (float*)d_ws;                          // n*128 f32
    float* asrc = xp + (size_t)n * HC;                   // n*4
    float* adst = asrc + (size_t)n * HEADS;              // n*4
    int*   cnt    = (int*)(adst + (size_t)n * HEADS);    // n
    int*   offs   = cnt + n;                             // n+1
    int*   cursor = offs + n + 1;                        // n
    int*   bsum   = cursor + n;                          // NB
    int*   srcs   = bsum + 1024;                         // E+n

    k_gemm<<<dim3((n + BM - 1) / BM), 256, 0, stream>>>(x, W, att_src, att_dst, xp, asrc, adst, cnt, n);
    k_count<<<(E + 255) / 256, 256, 0, stream>>>(ei, cnt, E);
    k_scan1<<<NB, 256, 0, stream>>>(cnt, bsum, n);
    k_scan2<<<1, 1024, 0, stream>>>(bsum, offs, NB, n, EN);
    k_scan3<<<NB, 256, 0, stream>>>(cnt, bsum, offs, cursor, n);
    k_fill<<<(EN + 255) / 256, 256, 0, stream>>>(ei, cursor, srcs, E, n);
    k_gat<<<(n + 3) / 4, 256, 0, stream>>>(offs, srcs, asrc, adst, xp, bias, out, n);
}